// Round 3
// baseline (373.571 us; speedup 1.0000x reference)
//
#include <hip/hip_runtime.h>
#include <stdint.h>

#define T_TOK 8192
#define NEXP  8
#define DIMSZ 1024
#define HIDSZ 2048
#define MAX_MT (T_TOK / 128 + NEXP - 1)   // 71: worst-case total m-tiles

typedef __attribute__((ext_vector_type(4))) float f32x4;
typedef __attribute__((ext_vector_type(8))) short s16x8;

// ---------- helpers ----------

__device__ __forceinline__ uint16_t f2bf(float f) {
  uint32_t u = __builtin_bit_cast(uint32_t, f);
  u += 0x7fffu + ((u >> 16) & 1u);   // RNE
  return (uint16_t)(u >> 16);
}

// async global->LDS, 16B per lane; LDS dst = wave-uniform base + lane*16.
__device__ __forceinline__ void gload_lds16(const uint16_t* g, const uint16_t* lds_base) {
  __builtin_amdgcn_global_load_lds(
      (const __attribute__((address_space(1))) uint32_t*)(uintptr_t)g,
      (__attribute__((address_space(3))) uint32_t*)(uint32_t)(uintptr_t)lds_base,
      16, 0, 0);
}

// ---------- fused convert (+ offsets in block 0) ----------
// Static partition: blocks [0,1024) -> x, [1024,3072) -> w1, [3072,5120) -> w2.
// Each block converts a contiguous slab of 2048 float4 (32 KB of floats).
// Per thread: 8 float4, processed as 2 iters of 4 independent load->store.

__global__ void cvt_all(const float* __restrict__ x, const float* __restrict__ w1,
                        const float* __restrict__ w2, uint16_t* __restrict__ xb,
                        uint16_t* __restrict__ w1b, uint16_t* __restrict__ w2b,
                        const int* __restrict__ counts, int* __restrict__ offs,
                        int* __restrict__ toffs) {
  if (blockIdx.x == 0 && threadIdx.x == 0) {
    int s = 0, ts = 0;
    for (int e = 0; e < NEXP; ++e) {
      offs[e] = s; toffs[e] = ts;
      s += counts[e]; ts += (counts[e] + 127) >> 7;
    }
    offs[NEXP] = s; toffs[NEXP] = ts;
  }
  const int b = blockIdx.x;
  const float4* src; uint2* dst; size_t base;
  if (b < 1024)      { src = (const float4*)x;  dst = (uint2*)xb;  base = (size_t)b * 2048; }
  else if (b < 3072) { src = (const float4*)w1; dst = (uint2*)w1b; base = (size_t)(b - 1024) * 2048; }
  else               { src = (const float4*)w2; dst = (uint2*)w2b; base = (size_t)(b - 3072) * 2048; }

#pragma unroll
  for (int it = 0; it < 2; ++it) {
    const size_t i0 = base + (size_t)it * 1024 + threadIdx.x;
    float4 v[4];
#pragma unroll
    for (int j = 0; j < 4; ++j) v[j] = src[i0 + j * 256];
    uint2 o[4];
#pragma unroll
    for (int j = 0; j < 4; ++j) {
      o[j].x = f2bf(v[j].x) | ((uint32_t)f2bf(v[j].y) << 16);
      o[j].y = f2bf(v[j].z) | ((uint32_t)f2bf(v[j].w) << 16);
    }
#pragma unroll
    for (int j = 0; j < 4; ++j) dst[i0 + j * 256] = o[j];
  }
}

// ---------- grouped NT GEMM ----------
// C[m,n] = sum_k A[m,k] * B_e[n,k].  Tile 128x128, BK=32, 4 waves (2x2).
// nt-major compact grid: block b -> nt = b/MAX_MT, mtg = b%MAX_MT, so the
// 71 consecutive blocks of one nt-column share one B tile (L2 reuse); A is
// re-read per column but fits L3.  Expert from device tile-offset table.
// LDS chunk-swizzle: global 16B-chunk Q of row R lives at chunk Q^((R>>1)&3)
// => 2-way (free) bank access in both staging and ds_read.
template <bool OUT_BF16>
__global__ __launch_bounds__(256, 4)
void gemm_grouped(const uint16_t* __restrict__ A, const uint16_t* __restrict__ B,
                  void* __restrict__ C, const int* __restrict__ offs,
                  const int* __restrict__ toffs, int N, int K) {
  __shared__ __align__(16) uint16_t As[128 * 32];  // 8 KB
  __shared__ __align__(16) uint16_t Bs[128 * 32];  // 8 KB

  const unsigned nt  = blockIdx.x / MAX_MT;
  const unsigned mtg = blockIdx.x % MAX_MT;
  if ((int)mtg >= toffs[NEXP]) return;
  int e = 0;
#pragma unroll
  for (int i = 1; i < NEXP; ++i) e += (toffs[i] <= (int)mtg) ? 1 : 0;
  const int mt      = (int)mtg - toffs[e];
  const int m_start = offs[e];
  const int m_count = offs[e + 1] - m_start;
  const int m0      = mt * 128;
  int valid_m = m_count - m0;
  if (valid_m > 128) valid_m = 128;
  const int n0 = (int)nt * 128;

  const int tid  = threadIdx.x;
  const int w    = tid >> 6;
  const int lane = tid & 63;
  const int wm = w & 1, wn = w >> 1;

  // Staging map (with swizzle): wave w fills 1KB chunks w and w+4.
  const int srow0 = w * 16 + (lane >> 2);
  const int srow1 = (w + 4) * 16 + (lane >> 2);
  const int scol  = (((lane & 3) ^ ((lane >> 3) & 3))) * 8;

  const uint16_t* gA = A + (size_t)m_start * K;
  const uint16_t* gB = B + (size_t)e * N * K;

  const int ar0 = m0 + (srow0 < valid_m ? srow0 : valid_m - 1);
  const int ar1 = m0 + (srow1 < valid_m ? srow1 : valid_m - 1);

  const uint16_t* a0p = gA + (size_t)ar0 * K + scol;
  const uint16_t* a1p = gA + (size_t)ar1 * K + scol;
  const uint16_t* b0p = gB + (size_t)(n0 + srow0) * K + scol;
  const uint16_t* b1p = gB + (size_t)(n0 + srow1) * K + scol;

  const uint16_t* lA0 = &As[w * 512];
  const uint16_t* lA1 = &As[(w + 4) * 512];
  const uint16_t* lB0 = &Bs[w * 512];
  const uint16_t* lB1 = &Bs[(w + 4) * 512];

  // Fragment read (swizzled): k-chunk q = lane>>4 lives at chunk q^((fr>>1)&3).
  const int fr = lane & 15;
  const int fk = ((lane >> 4) ^ ((fr >> 1) & 3)) * 8;

  f32x4 acc[4][4];
#pragma unroll
  for (int mi = 0; mi < 4; ++mi)
#pragma unroll
    for (int ni = 0; ni < 4; ++ni) acc[mi][ni] = (f32x4){0.f, 0.f, 0.f, 0.f};

  for (int k0 = 0; k0 < K; k0 += 32) {
    __syncthreads();
    gload_lds16(a0p, lA0);
    gload_lds16(a1p, lA1);
    gload_lds16(b0p, lB0);
    gload_lds16(b1p, lB1);
    a0p += 32; a1p += 32; b0p += 32; b1p += 32;
    __syncthreads();

    s16x8 af[4], bf[4];
#pragma unroll
    for (int mi = 0; mi < 4; ++mi)
      af[mi] = *(const s16x8*)&As[(wm * 64 + mi * 16 + fr) * 32 + fk];
#pragma unroll
    for (int ni = 0; ni < 4; ++ni)
      bf[ni] = *(const s16x8*)&Bs[(wn * 64 + ni * 16 + fr) * 32 + fk];
#pragma unroll
    for (int mi = 0; mi < 4; ++mi)
#pragma unroll
      for (int ni = 0; ni < 4; ++ni)
        acc[mi][ni] = __builtin_amdgcn_mfma_f32_16x16x32_bf16(af[mi], bf[ni], acc[mi][ni], 0, 0, 0);
  }

  // Epilogue. C/D 16x16 layout: col = lane&15, row = (lane>>4)*4 + reg.
  const int cq = (lane >> 4) * 4;
  const int cc = lane & 15;
#pragma unroll
  for (int mi = 0; mi < 4; ++mi) {
#pragma unroll
    for (int r = 0; r < 4; ++r) {
      const int rt = wm * 64 + mi * 16 + cq + r;
      if (rt < valid_m) {
        const size_t rowoff = (size_t)(m_start + m0 + rt) * N;
#pragma unroll
        for (int ni = 0; ni < 4; ++ni) {
          const int col = n0 + wn * 64 + ni * 16 + cc;
          const float v = acc[mi][ni][r];
          if (OUT_BF16) {
            ((uint16_t*)C)[rowoff + col] = f2bf(v);
          } else {
            const uint32_t b = (uint32_t)f2bf(v) << 16;
            ((float*)C)[rowoff + col] = __builtin_bit_cast(float, b);
          }
        }
      }
    }
  }
}

// ---------- launch ----------

extern "C" void kernel_launch(void* const* d_in, const int* in_sizes, int n_in,
                              void* d_out, int out_size, void* d_ws, size_t ws_size,
                              hipStream_t stream) {
  const float* x  = (const float*)d_in[0];   // [T, DIM]
  const float* w1 = (const float*)d_in[1];   // [E, HID, DIM]
  const float* w2 = (const float*)d_in[2];   // [E, DIM, HID]
  const int* cnt  = (const int*)d_in[3];     // [E]
  float* out = (float*)d_out;                // [T, DIM] f32

  char* ws = (char*)d_ws;
  uint16_t* xb  = (uint16_t*)(ws);                      // 16 MB  [T, DIM] bf16
  uint16_t* w1b = (uint16_t*)(ws + 16777216);           // 32 MB  [E, HID, DIM] bf16
  uint16_t* w2b = (uint16_t*)(ws + 50331648);           // 32 MB  [E, DIM, HID] bf16
  uint16_t* h   = (uint16_t*)(ws + 83886080);           // 32 MB  [T, HID] bf16
  int* offs     = (int*)(ws + 117440512);               // 9 ints
  int* toffs    = offs + 9;                             // 9 ints

  cvt_all<<<5120, 256, 0, stream>>>(x, w1, w2, xb, w1b, w2b, cnt, offs, toffs);

  // GEMM1: h = xb @ w1b^T  (N=HID=2048 -> 16 n-tiles, K=DIM)
  gemm_grouped<true><<<16 * MAX_MT, 256, 0, stream>>>(
      xb, w1b, (void*)h, offs, toffs, HIDSZ, DIMSZ);

  // GEMM2: out = h @ w2b^T  (N=DIM=1024 -> 8 n-tiles, K=HID)
  gemm_grouped<false><<<8 * MAX_MT, 256, 0, stream>>>(
      h, w2b, (void*)out, offs, toffs, DIMSZ, HIDSZ);
}

// Round 4
// 298.582 us; speedup vs baseline: 1.2512x; 1.2512x over previous
//
#include <hip/hip_runtime.h>
#include <stdint.h>

#define T_TOK 8192
#define NEXP  8
#define DIMSZ 1024
#define HIDSZ 2048
#define MAX_MT (T_TOK / 128 + NEXP - 1)   // 71: worst-case total m-tiles

typedef __attribute__((ext_vector_type(4))) float f32x4;
typedef __attribute__((ext_vector_type(8))) short s16x8;

// ---------- helpers ----------

__device__ __forceinline__ uint16_t f2bf(float f) {
  uint32_t u = __builtin_bit_cast(uint32_t, f);
  u += 0x7fffu + ((u >> 16) & 1u);   // RNE
  return (uint16_t)(u >> 16);
}

// async global->LDS, 16B per lane; LDS dst = wave-uniform base + lane*16.
__device__ __forceinline__ void gload_lds16(const uint16_t* g, const uint16_t* lds_base) {
  __builtin_amdgcn_global_load_lds(
      (const __attribute__((address_space(1))) uint32_t*)(uintptr_t)g,
      (__attribute__((address_space(3))) uint32_t*)(uint32_t)(uintptr_t)lds_base,
      16, 0, 0);
}

// ---------- fused convert (+ offsets in block 0) ----------

__global__ void cvt_all(const float* __restrict__ x, const float* __restrict__ w1,
                        const float* __restrict__ w2, uint16_t* __restrict__ xb,
                        uint16_t* __restrict__ w1b, uint16_t* __restrict__ w2b,
                        const int* __restrict__ counts, int* __restrict__ offs,
                        int* __restrict__ toffs) {
  if (blockIdx.x == 0 && threadIdx.x == 0) {
    int s = 0, ts = 0;
    for (int e = 0; e < NEXP; ++e) {
      offs[e] = s; toffs[e] = ts;
      s += counts[e]; ts += (counts[e] + 127) >> 7;
    }
    offs[NEXP] = s; toffs[NEXP] = ts;
  }
  const int b = blockIdx.x;
  const float4* src; uint2* dst; size_t base;
  if (b < 1024)      { src = (const float4*)x;  dst = (uint2*)xb;  base = (size_t)b * 2048; }
  else if (b < 3072) { src = (const float4*)w1; dst = (uint2*)w1b; base = (size_t)(b - 1024) * 2048; }
  else               { src = (const float4*)w2; dst = (uint2*)w2b; base = (size_t)(b - 3072) * 2048; }

#pragma unroll
  for (int it = 0; it < 2; ++it) {
    const size_t i0 = base + (size_t)it * 1024 + threadIdx.x;
    float4 v[4];
#pragma unroll
    for (int j = 0; j < 4; ++j) v[j] = src[i0 + j * 256];
    uint2 o[4];
#pragma unroll
    for (int j = 0; j < 4; ++j) {
      o[j].x = f2bf(v[j].x) | ((uint32_t)f2bf(v[j].y) << 16);
      o[j].y = f2bf(v[j].z) | ((uint32_t)f2bf(v[j].w) << 16);
    }
#pragma unroll
    for (int j = 0; j < 4; ++j) dst[i0 + j * 256] = o[j];
  }
}

// ---------- grouped NT GEMM ----------
// C[m,n] = sum_k A[m,k] * B_e[n,k].  Tile 128x128, BK=32, 4 waves (2x2).
// XCD supertiling: HW assigns block b to XCD b%8 (round-robin heuristic;
// correctness-independent). xcd = b&7 picks a (m-group, n-group) region;
// slot = b>>3 walks the region. Blocks sharing an A/B panel are colocated
// on one XCD so each panel enters each L2 exactly once.
//   grid = 8 * mgs * ntg;  xcd -> (mg = xcd/ngx, ng = xcd%ngx)
//   slot -> (mt_in = slot%mgs, nt_in = slot/mgs)
// LDS chunk-swizzle: global 16B-chunk Q of row R lives at chunk Q^((R>>1)&3)
// => 2-way (free) bank access in both staging and ds_read (R3: conflicts=0).
template <bool OUT_BF16>
__global__ __launch_bounds__(256, 4)
void gemm_grouped(const uint16_t* __restrict__ A, const uint16_t* __restrict__ B,
                  void* __restrict__ C, const int* __restrict__ offs,
                  const int* __restrict__ toffs, int N, int K,
                  int mgs, int ntg, int ngx) {
  __shared__ __align__(16) uint16_t As[128 * 32];  // 8 KB
  __shared__ __align__(16) uint16_t Bs[128 * 32];  // 8 KB

  const int xcd  = blockIdx.x & 7;
  const int slot = blockIdx.x >> 3;
  const int mg = xcd / ngx;
  const int ng = xcd % ngx;
  const int mtg = mg * mgs + slot % mgs;
  const int nt  = ng * ntg + slot / mgs;
  if (mtg >= toffs[NEXP]) return;
  int e = 0;
#pragma unroll
  for (int i = 1; i < NEXP; ++i) e += (toffs[i] <= mtg) ? 1 : 0;
  const int mt      = mtg - toffs[e];
  const int m_start = offs[e];
  const int m_count = offs[e + 1] - m_start;
  const int m0      = mt * 128;
  int valid_m = m_count - m0;
  if (valid_m > 128) valid_m = 128;
  const int n0 = nt * 128;

  const int tid  = threadIdx.x;
  const int w    = tid >> 6;
  const int lane = tid & 63;
  const int wm = w & 1, wn = w >> 1;

  // Staging map (with swizzle): wave w fills 1KB chunks w and w+4.
  const int srow0 = w * 16 + (lane >> 2);
  const int srow1 = (w + 4) * 16 + (lane >> 2);
  const int scol  = (((lane & 3) ^ ((lane >> 3) & 3))) * 8;

  const uint16_t* gA = A + (size_t)m_start * K;
  const uint16_t* gB = B + (size_t)e * N * K;

  const int ar0 = m0 + (srow0 < valid_m ? srow0 : valid_m - 1);
  const int ar1 = m0 + (srow1 < valid_m ? srow1 : valid_m - 1);

  const uint16_t* a0p = gA + (size_t)ar0 * K + scol;
  const uint16_t* a1p = gA + (size_t)ar1 * K + scol;
  const uint16_t* b0p = gB + (size_t)(n0 + srow0) * K + scol;
  const uint16_t* b1p = gB + (size_t)(n0 + srow1) * K + scol;

  const uint16_t* lA0 = &As[w * 512];
  const uint16_t* lA1 = &As[(w + 4) * 512];
  const uint16_t* lB0 = &Bs[w * 512];
  const uint16_t* lB1 = &Bs[(w + 4) * 512];

  // Fragment read (swizzled): k-chunk q = lane>>4 lives at chunk q^((fr>>1)&3).
  const int fr = lane & 15;
  const int fk = ((lane >> 4) ^ ((fr >> 1) & 3)) * 8;

  f32x4 acc[4][4];
#pragma unroll
  for (int mi = 0; mi < 4; ++mi)
#pragma unroll
    for (int ni = 0; ni < 4; ++ni) acc[mi][ni] = (f32x4){0.f, 0.f, 0.f, 0.f};

  for (int k0 = 0; k0 < K; k0 += 32) {
    __syncthreads();
    gload_lds16(a0p, lA0);
    gload_lds16(a1p, lA1);
    gload_lds16(b0p, lB0);
    gload_lds16(b1p, lB1);
    a0p += 32; a1p += 32; b0p += 32; b1p += 32;
    __syncthreads();

    s16x8 af[4], bf[4];
#pragma unroll
    for (int mi = 0; mi < 4; ++mi)
      af[mi] = *(const s16x8*)&As[(wm * 64 + mi * 16 + fr) * 32 + fk];
#pragma unroll
    for (int ni = 0; ni < 4; ++ni)
      bf[ni] = *(const s16x8*)&Bs[(wn * 64 + ni * 16 + fr) * 32 + fk];
#pragma unroll
    for (int mi = 0; mi < 4; ++mi)
#pragma unroll
      for (int ni = 0; ni < 4; ++ni)
        acc[mi][ni] = __builtin_amdgcn_mfma_f32_16x16x32_bf16(af[mi], bf[ni], acc[mi][ni], 0, 0, 0);
  }

  // Epilogue. C/D 16x16 layout: col = lane&15, row = (lane>>4)*4 + reg.
  const int cq = (lane >> 4) * 4;
  const int cc = lane & 15;
#pragma unroll
  for (int mi = 0; mi < 4; ++mi) {
#pragma unroll
    for (int r = 0; r < 4; ++r) {
      const int rt = wm * 64 + mi * 16 + cq + r;
      if (rt < valid_m) {
        const size_t rowoff = (size_t)(m_start + m0 + rt) * N;
#pragma unroll
        for (int ni = 0; ni < 4; ++ni) {
          const int col = n0 + wn * 64 + ni * 16 + cc;
          const float v = acc[mi][ni][r];
          if (OUT_BF16) {
            ((uint16_t*)C)[rowoff + col] = f2bf(v);
          } else {
            const uint32_t b = (uint32_t)f2bf(v) << 16;
            ((float*)C)[rowoff + col] = __builtin_bit_cast(float, b);
          }
        }
      }
    }
  }
}

// ---------- launch ----------

extern "C" void kernel_launch(void* const* d_in, const int* in_sizes, int n_in,
                              void* d_out, int out_size, void* d_ws, size_t ws_size,
                              hipStream_t stream) {
  const float* x  = (const float*)d_in[0];   // [T, DIM]
  const float* w1 = (const float*)d_in[1];   // [E, HID, DIM]
  const float* w2 = (const float*)d_in[2];   // [E, DIM, HID]
  const int* cnt  = (const int*)d_in[3];     // [E]
  float* out = (float*)d_out;                // [T, DIM] f32

  char* ws = (char*)d_ws;
  uint16_t* xb  = (uint16_t*)(ws);                      // 16 MB  [T, DIM] bf16
  uint16_t* w1b = (uint16_t*)(ws + 16777216);           // 32 MB  [E, HID, DIM] bf16
  uint16_t* w2b = (uint16_t*)(ws + 50331648);           // 32 MB  [E, DIM, HID] bf16
  uint16_t* h   = (uint16_t*)(ws + 83886080);           // 32 MB  [T, HID] bf16
  int* offs     = (int*)(ws + 117440512);               // 9 ints
  int* toffs    = offs + 9;                             // 9 ints

  cvt_all<<<5120, 256, 0, stream>>>(x, w1, w2, xb, w1b, w2b, cnt, offs, toffs);

  // GEMM1: h = xb @ w1b^T  (N=HID, 16 nt).  XCDs: 4 m-groups x 2 n-groups.
  //   mgs=18 (4*18=72 >= 71 m-tiles), ntg=8, ngx=2.  grid = 8*18*8 = 1152.
  gemm_grouped<true><<<8 * 18 * 8, 256, 0, stream>>>(
      xb, w1b, (void*)h, offs, toffs, HIDSZ, DIMSZ, 18, 8, 2);

  // GEMM2: out = h @ w2b^T  (N=DIM, 8 nt).  XCDs: 8 m-groups x 1 n-group.
  //   mgs=9 (8*9=72 >= 71), ntg=8, ngx=1.  grid = 8*9*8 = 576.
  gemm_grouped<false><<<8 * 9 * 8, 256, 0, stream>>>(
      h, w2b, (void*)out, offs, toffs, DIMSZ, HIDSZ, 9, 8, 1);
}